// Round 10
// baseline (323.947 us; speedup 1.0000x reference)
//
#include <hip/hip_runtime.h>
#include <math.h>

// ---------------- tensor-product structure ----------------------------------
#define NPATH 11
#define SROW 1152       // x1 / out row length
#define SAMP 16         // samples per block (one MFMA tile)
#define NTHREADS 256    // 4 waves; block covers a 64-channel w-half

constexpr int H_L1[11]  = {0,0,0,1,1,1,1,2,2,2,2};
constexpr int H_L2[11]  = {0,1,2,0,1,1,2,0,1,2,2};
constexpr int H_LO[11]  = {0,1,2,1,0,2,1,2,1,0,2};
constexpr int H_N1[11]  = {1,1,1,3,3,3,3,5,5,5,5};
constexpr int H_N2[11]  = {1,3,5,1,3,3,5,1,3,5,5};
constexpr int H_N3[11]  = {1,3,5,3,1,5,3,5,3,1,5};
constexpr int H_PIB[12] = {0,1,2,3,6,9,12,15,20,25,30,35};  // prefix sum of N1
constexpr int H_MOFF[12]  = {0,1,4,9,18,21,36,45,70,85,90,115};
constexpr int H_W3OFF[12] = {0,1,10,35,44,53,98,143,168,213,238,363};
constexpr int H_X2OFF[3]  = {0,1,4};
constexpr int H_CBASE[3]  = {0,1,4};   // x1T column base per l1
constexpr int H_KCB[3]    = {0,1,4};   // output k-column base per lo
constexpr float H_PW[3] = {0.05103103630798288f, 0.07654655446197431f, 0.09882117688026186f};

// ================= compile-time Wigner 3j (exact port of reference) =========
namespace w3c {

constexpr double fact(int n) {
    double r = 1.0;
    for (int i = 2; i <= n; ++i) r *= (double)i;
    return r;
}

constexpr double csqrt(double x) {
    if (x <= 0.0) return 0.0;
    double g = x < 1.0 ? 1.0 : x;
    for (int i = 0; i < 100; ++i) g = 0.5 * (g + x / g);
    return g;
}

constexpr double su2_cg(int j1, int m1, int j2, int m2, int j3, int m3) {
    if (m3 != m1 + m2) return 0.0;
    int vmin = -j1 + j2 + m3;
    if (-j1 + m1 > vmin) vmin = -j1 + m1;
    if (0 > vmin) vmin = 0;
    int vmax = j2 + j3 + m1;
    if (j3 - j1 + j2 < vmax) vmax = j3 - j1 + j2;
    if (j3 + m3 < vmax) vmax = j3 + m3;
    if (vmax < vmin) return 0.0;
    double pref = (2.0 * j3 + 1.0) *
        (fact(j3 + j1 - j2) * fact(j3 - j1 + j2) * fact(j1 + j2 - j3) *
         fact(j3 + m3) * fact(j3 - m3)) /
        (fact(j1 + j2 + j3 + 1) * fact(j1 - m1) * fact(j1 + m1) *
         fact(j2 - m2) * fact(j2 + m2));
    double S = 0.0;
    for (int v = vmin; v <= vmax; ++v) {
        double sgn = ((v + j2 + m2) & 1) ? -1.0 : 1.0;
        S += sgn * (fact(j2 + j3 + m1 - v) * fact(j1 - m1 + v)) /
             (fact(v) * fact(j3 - j1 + j2 - v) * fact(j3 + m3 - v) *
              fact(v + j1 - j2 - m3));
    }
    return csqrt(pref) * S;
}

struct Q { double re[5][5]; double im[5][5]; };

constexpr Q build_q(int l) {
    Q q{};
    double s = csqrt(0.5);
    for (int m = -l; m < 0; ++m) {
        q.re[l + m][l - m] = s;
        q.im[l + m][l + m] = -s;
    }
    q.re[l][l] = 1.0;
    for (int m = 1; m <= l; ++m) {
        double sg = (m & 1) ? -1.0 : 1.0;
        q.re[l + m][l + m] = sg * s;
        q.im[l + m][l - m] = sg * s;
    }
    double fr = 1.0, fi = 0.0;
    if (l == 1) { fr = 0.0; fi = -1.0; }
    else if (l == 2) { fr = -1.0; fi = 0.0; }
    for (int r = 0; r < 5; ++r)
        for (int c = 0; c < 5; ++c) {
            double a = q.re[r][c], b = q.im[r][c];
            q.re[r][c] = a * fr - b * fi;
            q.im[r][c] = a * fi + b * fr;
        }
    return q;
}

struct PathW { float v[125]; };

constexpr PathW make_path(int l1, int l2, int l3) {
    int n1 = 2 * l1 + 1, n2 = 2 * l2 + 1, n3 = 2 * l3 + 1;
    double C[5][5][5] = {};
    for (int m1 = -l1; m1 <= l1; ++m1)
        for (int m2 = -l2; m2 <= l2; ++m2) {
            int m3 = m1 + m2;
            if (m3 >= -l3 && m3 <= l3)
                C[m1 + l1][m2 + l2][m3 + l3] = su2_cg(l1, m1, l2, m2, l3, m3);
        }
    Q q1 = build_q(l1), q2 = build_q(l2), q3 = build_q(l3);

    double Cr[5][5][5] = {}, Ci[5][5][5] = {};
    for (int j = 0; j < n1; ++j)
        for (int l = 0; l < n2; ++l)
            for (int m = 0; m < n3; ++m) {
                double ar = 0.0, ai = 0.0;
                for (int i = 0; i < n1; ++i)
                    for (int k = 0; k < n2; ++k) {
                        double t1r = q1.re[i][j], t1i = q1.im[i][j];
                        double t2r = q2.re[k][l], t2i = q2.im[k][l];
                        double tr = t1r * t2r - t1i * t2i;
                        double ti = t1r * t2i + t1i * t2r;
                        for (int n = 0; n < n3; ++n) {
                            double c = C[i][k][n];
                            if (c == 0.0) continue;
                            double pr = q3.re[n][m], pi = -q3.im[n][m];
                            ar += c * (tr * pr - ti * pi);
                            ai += c * (tr * pi + ti * pr);
                        }
                    }
                Cr[j][l][m] = ar;
                Ci[j][l][m] = ai;
            }

    double nr = 0.0, ni = 0.0;
    for (int j = 0; j < n1; ++j)
        for (int l = 0; l < n2; ++l)
            for (int m = 0; m < n3; ++m) {
                nr += Cr[j][l][m] * Cr[j][l][m];
                ni += Ci[j][l][m] * Ci[j][l][m];
            }
    nr = csqrt(nr);
    ni = csqrt(ni);
    bool useR = (nr >= ni);
    double norm = useR ? nr : ni;

    PathW out{};
    int idx = 0;
    for (int j = 0; j < n1; ++j)
        for (int l = 0; l < n2; ++l)
            for (int m = 0; m < n3; ++m)
                out.v[idx++] = (float)((useR ? Cr[j][l][m] : Ci[j][l][m]) / norm);
    return out;
}

constexpr PathW P0  = make_path(0,0,0);
constexpr PathW P1  = make_path(0,1,1);
constexpr PathW P2  = make_path(0,2,2);
constexpr PathW P3  = make_path(1,0,1);
constexpr PathW P4  = make_path(1,1,0);
constexpr PathW P5  = make_path(1,1,2);
constexpr PathW P6  = make_path(1,2,1);
constexpr PathW P7  = make_path(2,0,2);
constexpr PathW P8  = make_path(2,1,1);
constexpr PathW P9  = make_path(2,2,0);
constexpr PathW P10 = make_path(2,2,2);

struct W3All { float v[363]; };

constexpr W3All make_all() {
    W3All a{};
    const PathW* ps[11] = {&P0,&P1,&P2,&P3,&P4,&P5,&P6,&P7,&P8,&P9,&P10};
    for (int p = 0; p < 11; ++p) {
        int n = H_W3OFF[p+1] - H_W3OFF[p];
        for (int i = 0; i < n; ++i) a.v[H_W3OFF[p] + i] = ps[p]->v[i];
    }
    return a;
}

} // namespace w3c

__device__ __constant__ w3c::W3All c_W3 = w3c::make_all();

// ---------------- helpers ----------------------------------------------------
typedef float f32x4 __attribute__((ext_vector_type(4)));
typedef __bf16 bf16x8 __attribute__((ext_vector_type(8)));

__device__ __forceinline__ unsigned short f2bf(float f) {
    union { float f; unsigned int u; } v; v.f = f;
    unsigned int u = v.u + 0x7fffu + ((v.u >> 16) & 1u);   // RNE
    return (unsigned short)(u >> 16);
}
__device__ __forceinline__ float bf2f(unsigned short h) {
    union { unsigned int u; float f; } v; v.u = ((unsigned int)h) << 16;
    return v.f;
}

#define MFMA(a, b, c) __builtin_amdgcn_mfma_f32_16x16x32_bf16((a), (b), (c), 0, 0, 0)

// ---------------- weight prep: pure gather, one thread per element -----------
// whi/wlo layout: [p][w][u]  (u contiguous)
__global__ __launch_bounds__(256) void wprep_kernel(
    const float* __restrict__ w, unsigned short* __restrict__ whi,
    unsigned short* __restrict__ wlo)
{
    int idx = blockIdx.x * 256 + threadIdx.x;
    if (idx >= NPATH * 128 * 128) return;
    int p   = idx / 16384;
    int rem = idx - p * 16384;
    int wc  = rem >> 7;     // w channel
    int u   = rem & 127;
    float f = w[p * 16384 + u * 128 + wc];
    unsigned short hi = f2bf(f);
    unsigned short lo = f2bf(f - bf2f(hi));
    whi[idx] = hi;
    wlo[idx] = lo;
}

// ---------------- pass over NP l1-homogeneous paths --------------------------
// A fragments (all NP paths x 4 ub, hi+lo) are prefetched up front — with a
// >128-VGPR budget these loads stay in flight instead of serializing on L2.
// B fragments are read once per ub and shared by all NP paths.
// D layout (m89-verified): col = lane&15 -> sample n; row = (lane>>4)*4+reg -> w-off.
template<int P0G, int NP, int CB, int NC>
__device__ __forceinline__ void gemm_pass(
    const unsigned short* __restrict__ whi, const unsigned short* __restrict__ wlo,
    const unsigned short (*sB)[16][136],
    const float* sM35,
    float (&ov)[4][9], int r16, int q4, int wrow)
{
    // prefetch all A fragments for this pass (NP*4 hi + NP*4 lo, 16B each)
    bf16x8 Ah[NP][4], Al[NP][4];
    #pragma unroll
    for (int pp = 0; pp < NP; ++pp)
        #pragma unroll
        for (int ub = 0; ub < 4; ++ub) {
            const size_t aoff =
                ((size_t)((P0G + pp) * 128 + wrow)) * 128 + ub * 32 + q4 * 8;
            Ah[pp][ub] = *(const bf16x8*)&whi[aoff];
            Al[pp][ub] = *(const bf16x8*)&wlo[aoff];
        }

    f32x4 acc[NP][NC];
    #pragma unroll
    for (int pp = 0; pp < NP; ++pp)
        #pragma unroll
        for (int i = 0; i < NC; ++i) acc[pp][i] = (f32x4)(0.0f);

    #pragma unroll
    for (int ub = 0; ub < 4; ++ub) {
        const int ko = ub * 32 + q4 * 8;
        bf16x8 B[NC];
        #pragma unroll
        for (int c = 0; c < NC; ++c)
            B[c] = *(const bf16x8*)&sB[CB + c][r16][ko];
        #pragma unroll
        for (int pp = 0; pp < NP; ++pp)
            #pragma unroll
            for (int i = 0; i < NC; ++i) {
                acc[pp][i] = MFMA(Ah[pp][ub], B[i], acc[pp][i]);
                acc[pp][i] = MFMA(Al[pp][ub], B[i], acc[pp][i]);
            }
    }

    // fold into ov (indices identical to round-7/8 verified version)
    #pragma unroll
    for (int pp = 0; pp < NP; ++pp) {
        const int P = P0G + pp;
        #pragma unroll
        for (int i = 0; i < NC; ++i)
            #pragma unroll
            for (int k = 0; k < H_N3[P]; ++k) {
                const float mv = sM35[r16 * 175 + (H_PIB[P] + i) * 5 + k];
                #pragma unroll
                for (int r = 0; r < 4; ++r)
                    ov[r][H_KCB[H_LO[P]] + k] += acc[pp][i][r] * mv;
            }
    }
}

// ---------------- main kernel ------------------------------------------------
// Block = 16 samples x 64 output channels (w-half bh = blockIdx.x).
// LDS: sB [9][16][136] ushort (39168 B) + sM35 [16*175] f32 (11200 B) = 50368 B
//      -> 3 blocks/CU by LDS. Epilogue sOut[16][580] f32 (37120 B) aliases sB.
__global__ __launch_bounds__(NTHREADS, 1) void fctp_kernel(
    const float* __restrict__ x1, const float* __restrict__ x2,
    const unsigned short* __restrict__ whi, const unsigned short* __restrict__ wlo,
    float* __restrict__ out, int N)
{
    __shared__ __align__(16) unsigned char smem[50368];
    unsigned short (*sB)[16][136] = (unsigned short (*)[16][136])smem;
    float* sM35 = (float*)(smem + 39168);

    const int tid  = threadIdx.x;
    const int lane = tid & 63;
    const int wt   = tid >> 6;          // 0..3
    const int bh   = blockIdx.x;        // w-half: 0 or 1
    const int n0   = blockIdx.y * SAMP;

    // ---- stage X1 -> bf16 in sB, float4 loads (col/u map verified r4) ----
    for (int e = tid; e < SAMP * (SROW / 4); e += NTHREADS) {
        int n  = e / (SROW / 4);
        int c4 = (e % (SROW / 4)) * 4;
        f32x4 v;
        if (n0 + n < N) v = *(const f32x4*)&x1[(size_t)(n0 + n) * SROW + c4];
        else            v = (f32x4)(0.0f);
        #pragma unroll
        for (int j = 0; j < 4; ++j) {
            int c = c4 + j;
            int col, u;
            if (c < 128)       { col = 0;           u = c; }
            else if (c < 512)  { int rr = c - 128;  u = rr / 3; col = 1 + rr % 3; }
            else               { int rr = c - 512;  u = rr / 5; col = 4 + rr % 5; }
            sB[col][n][u] = f2bf(v[j]);
        }
    }

    // ---- stage PW * M_p[n,i,k] into sM35 (verified r4, byte-identical) ----
    for (int e = tid; e < SAMP * 115; e += NTHREADS) {
        int n = e / 115, m = e % 115;
        float val = 0.0f;
        int pi5 = 0;
        #pragma unroll
        for (int p = 0; p < NPATH; ++p) {
            if (m >= H_MOFF[p] && m < H_MOFF[p + 1]) {
                const int n2 = H_N2[p], n3 = H_N3[p];
                int rr = m - H_MOFF[p];
                int i = rr / n3, k = rr % n3;
                if (n0 + n < N) {
                    const float* Cp  = c_W3.v + H_W3OFF[p];
                    const float* x2p = x2 + (size_t)(n0 + n) * 9 + H_X2OFF[H_L2[p]];
                    float a = 0.0f;
                    #pragma unroll
                    for (int j = 0; j < n2; ++j)
                        a += Cp[(i * n2 + j) * n3 + k] * x2p[j];
                    val = H_PW[H_LO[p]] * a;
                }
                pi5 = (H_PIB[p] + i) * 5 + k;
            }
        }
        sM35[n * 175 + pi5] = val;
    }
    __syncthreads();

    // ---- MFMA GEMM in 5 l1-homogeneous passes ----
    const int r16  = lane & 15;              // A row (w-offset) / B col (sample)
    const int q4   = lane >> 4;
    const int wrow = bh * 64 + wt * 16 + r16;  // global weight row for A frags

    float ov[4][9];
    #pragma unroll
    for (int r = 0; r < 4; ++r)
        #pragma unroll
        for (int j = 0; j < 9; ++j) ov[r][j] = 0.0f;

    gemm_pass<0, 3, 0, 1>(whi, wlo, sB, sM35, ov, r16, q4, wrow);  // p0-2, col 0
    gemm_pass<3, 2, 1, 3>(whi, wlo, sB, sM35, ov, r16, q4, wrow);  // p3,4 cols 1-3
    gemm_pass<5, 2, 1, 3>(whi, wlo, sB, sM35, ov, r16, q4, wrow);  // p5,6 cols 1-3
    gemm_pass<7, 2, 4, 5>(whi, wlo, sB, sM35, ov, r16, q4, wrow);  // p7,8 cols 4-8
    gemm_pass<9, 2, 4, 5>(whi, wlo, sB, sM35, ov, r16, q4, wrow);  // p9,10 cols 4-8

    // ---- epilogue: sOut[16][580] aliases sB region (sM35 region untouched) --
    // sOut row layout (w' = within-half channel 0..63):
    //   [0,64)    : lo=0, col w'
    //   [64,256)  : lo=1, col w'*3+k
    //   [256,576) : lo=2, col w'*5+k
    __syncthreads();
    float* sOut = (float*)smem;
    const int wp = wt * 16 + q4 * 4;    // within-half base channel for this lane
    {
        float* so = &sOut[r16 * 580];
        #pragma unroll
        for (int r = 0; r < 4; ++r) {
            const int w = wp + r;
            so[w] = ov[r][0];
            #pragma unroll
            for (int k = 0; k < 3; ++k) so[64 + w * 3 + k] = ov[r][1 + k];
            #pragma unroll
            for (int k = 0; k < 5; ++k) so[256 + w * 5 + k] = ov[r][4 + k];
        }
    }
    __syncthreads();

    // vectorized store of the block's 3 contiguous output runs per sample
    for (int e = tid; e < SAMP * 144; e += NTHREADS) {
        int nn = e / 144, c4 = (e % 144) * 4;
        int gn = n0 + nn;
        if (gn >= N) break;
        f32x4 v = *(const f32x4*)&sOut[nn * 580 + c4];
        size_t base = (size_t)gn * SROW;
        size_t off;
        if (c4 < 64)        off = base + bh * 64 + c4;
        else if (c4 < 256)  off = base + 128 + bh * 192 + (c4 - 64);
        else                off = base + 512 + bh * 320 + (c4 - 256);
        *(f32x4*)&out[off] = v;
    }
}

// ---------------- launch -----------------------------------------------------
extern "C" void kernel_launch(void* const* d_in, const int* in_sizes, int n_in,
                              void* d_out, int out_size, void* d_ws, size_t ws_size,
                              hipStream_t stream) {
    const float* x1 = (const float*)d_in[0];
    const float* x2 = (const float*)d_in[1];
    const float* wt = (const float*)d_in[2];
    float* out = (float*)d_out;

    unsigned short* whi = (unsigned short*)d_ws;
    unsigned short* wlo = whi + (size_t)NPATH * 128 * 128;

    int N = in_sizes[0] / SROW;

    hipLaunchKernelGGL(wprep_kernel, dim3((NPATH * 128 * 128 + 255) / 256),
                       dim3(256), 0, stream, wt, whi, wlo);

    int tiles = (N + SAMP - 1) / SAMP;
    hipLaunchKernelGGL(fctp_kernel, dim3(2, tiles), dim3(NTHREADS), 0, stream,
                       x1, x2, whi, wlo, out, N);
}

// Round 11
// 131.122 us; speedup vs baseline: 2.4706x; 2.4706x over previous
//
#include <hip/hip_runtime.h>
#include <math.h>

// ---------------- tensor-product structure ----------------------------------
#define NPATH 11
#define SROW 1152       // x1 / out row length
#define SAMP 16         // samples per block (one MFMA tile)
#define NTHREADS 512    // 8 waves; wave wt owns output channels [wt*16, wt*16+16)

constexpr int H_L1[11]  = {0,0,0,1,1,1,1,2,2,2,2};
constexpr int H_L2[11]  = {0,1,2,0,1,1,2,0,1,2,2};
constexpr int H_LO[11]  = {0,1,2,1,0,2,1,2,1,0,2};
constexpr int H_N1[11]  = {1,1,1,3,3,3,3,5,5,5,5};
constexpr int H_N2[11]  = {1,3,5,1,3,3,5,1,3,5,5};
constexpr int H_N3[11]  = {1,3,5,3,1,5,3,5,3,1,5};
constexpr int H_PIB[12] = {0,1,2,3,6,9,12,15,20,25,30,35};  // prefix sum of N1
constexpr int H_MOFF[12]  = {0,1,4,9,18,21,36,45,70,85,90,115};
constexpr int H_W3OFF[12] = {0,1,10,35,44,53,98,143,168,213,238,363};
constexpr int H_X2OFF[3]  = {0,1,4};
constexpr int H_CBASE[3]  = {0,1,4};   // x1T column base per l1
constexpr int H_KCB[3]    = {0,1,4};   // output k-column base per lo
constexpr float H_PW[3] = {0.05103103630798288f, 0.07654655446197431f, 0.09882117688026186f};

// ================= compile-time Wigner 3j (exact port of reference) =========
namespace w3c {

constexpr double fact(int n) {
    double r = 1.0;
    for (int i = 2; i <= n; ++i) r *= (double)i;
    return r;
}

constexpr double csqrt(double x) {
    if (x <= 0.0) return 0.0;
    double g = x < 1.0 ? 1.0 : x;
    for (int i = 0; i < 100; ++i) g = 0.5 * (g + x / g);
    return g;
}

constexpr double su2_cg(int j1, int m1, int j2, int m2, int j3, int m3) {
    if (m3 != m1 + m2) return 0.0;
    int vmin = -j1 + j2 + m3;
    if (-j1 + m1 > vmin) vmin = -j1 + m1;
    if (0 > vmin) vmin = 0;
    int vmax = j2 + j3 + m1;
    if (j3 - j1 + j2 < vmax) vmax = j3 - j1 + j2;
    if (j3 + m3 < vmax) vmax = j3 + m3;
    if (vmax < vmin) return 0.0;
    double pref = (2.0 * j3 + 1.0) *
        (fact(j3 + j1 - j2) * fact(j3 - j1 + j2) * fact(j1 + j2 - j3) *
         fact(j3 + m3) * fact(j3 - m3)) /
        (fact(j1 + j2 + j3 + 1) * fact(j1 - m1) * fact(j1 + m1) *
         fact(j2 - m2) * fact(j2 + m2));
    double S = 0.0;
    for (int v = vmin; v <= vmax; ++v) {
        double sgn = ((v + j2 + m2) & 1) ? -1.0 : 1.0;
        S += sgn * (fact(j2 + j3 + m1 - v) * fact(j1 - m1 + v)) /
             (fact(v) * fact(j3 - j1 + j2 - v) * fact(j3 + m3 - v) *
              fact(v + j1 - j2 - m3));
    }
    return csqrt(pref) * S;
}

struct Q { double re[5][5]; double im[5][5]; };

constexpr Q build_q(int l) {
    Q q{};
    double s = csqrt(0.5);
    for (int m = -l; m < 0; ++m) {
        q.re[l + m][l - m] = s;
        q.im[l + m][l + m] = -s;
    }
    q.re[l][l] = 1.0;
    for (int m = 1; m <= l; ++m) {
        double sg = (m & 1) ? -1.0 : 1.0;
        q.re[l + m][l + m] = sg * s;
        q.im[l + m][l - m] = sg * s;
    }
    double fr = 1.0, fi = 0.0;
    if (l == 1) { fr = 0.0; fi = -1.0; }
    else if (l == 2) { fr = -1.0; fi = 0.0; }
    for (int r = 0; r < 5; ++r)
        for (int c = 0; c < 5; ++c) {
            double a = q.re[r][c], b = q.im[r][c];
            q.re[r][c] = a * fr - b * fi;
            q.im[r][c] = a * fi + b * fr;
        }
    return q;
}

struct PathW { float v[125]; };

constexpr PathW make_path(int l1, int l2, int l3) {
    int n1 = 2 * l1 + 1, n2 = 2 * l2 + 1, n3 = 2 * l3 + 1;
    double C[5][5][5] = {};
    for (int m1 = -l1; m1 <= l1; ++m1)
        for (int m2 = -l2; m2 <= l2; ++m2) {
            int m3 = m1 + m2;
            if (m3 >= -l3 && m3 <= l3)
                C[m1 + l1][m2 + l2][m3 + l3] = su2_cg(l1, m1, l2, m2, l3, m3);
        }
    Q q1 = build_q(l1), q2 = build_q(l2), q3 = build_q(l3);

    double Cr[5][5][5] = {}, Ci[5][5][5] = {};
    for (int j = 0; j < n1; ++j)
        for (int l = 0; l < n2; ++l)
            for (int m = 0; m < n3; ++m) {
                double ar = 0.0, ai = 0.0;
                for (int i = 0; i < n1; ++i)
                    for (int k = 0; k < n2; ++k) {
                        double t1r = q1.re[i][j], t1i = q1.im[i][j];
                        double t2r = q2.re[k][l], t2i = q2.im[k][l];
                        double tr = t1r * t2r - t1i * t2i;
                        double ti = t1r * t2i + t1i * t2r;
                        for (int n = 0; n < n3; ++n) {
                            double c = C[i][k][n];
                            if (c == 0.0) continue;
                            double pr = q3.re[n][m], pi = -q3.im[n][m];
                            ar += c * (tr * pr - ti * pi);
                            ai += c * (tr * pi + ti * pr);
                        }
                    }
                Cr[j][l][m] = ar;
                Ci[j][l][m] = ai;
            }

    double nr = 0.0, ni = 0.0;
    for (int j = 0; j < n1; ++j)
        for (int l = 0; l < n2; ++l)
            for (int m = 0; m < n3; ++m) {
                nr += Cr[j][l][m] * Cr[j][l][m];
                ni += Ci[j][l][m] * Ci[j][l][m];
            }
    nr = csqrt(nr);
    ni = csqrt(ni);
    bool useR = (nr >= ni);
    double norm = useR ? nr : ni;

    PathW out{};
    int idx = 0;
    for (int j = 0; j < n1; ++j)
        for (int l = 0; l < n2; ++l)
            for (int m = 0; m < n3; ++m)
                out.v[idx++] = (float)((useR ? Cr[j][l][m] : Ci[j][l][m]) / norm);
    return out;
}

constexpr PathW P0  = make_path(0,0,0);
constexpr PathW P1  = make_path(0,1,1);
constexpr PathW P2  = make_path(0,2,2);
constexpr PathW P3  = make_path(1,0,1);
constexpr PathW P4  = make_path(1,1,0);
constexpr PathW P5  = make_path(1,1,2);
constexpr PathW P6  = make_path(1,2,1);
constexpr PathW P7  = make_path(2,0,2);
constexpr PathW P8  = make_path(2,1,1);
constexpr PathW P9  = make_path(2,2,0);
constexpr PathW P10 = make_path(2,2,2);

struct W3All { float v[363]; };

constexpr W3All make_all() {
    W3All a{};
    const PathW* ps[11] = {&P0,&P1,&P2,&P3,&P4,&P5,&P6,&P7,&P8,&P9,&P10};
    for (int p = 0; p < 11; ++p) {
        int n = H_W3OFF[p+1] - H_W3OFF[p];
        for (int i = 0; i < n; ++i) a.v[H_W3OFF[p] + i] = ps[p]->v[i];
    }
    return a;
}

} // namespace w3c

__device__ __constant__ w3c::W3All c_W3 = w3c::make_all();

// ---------------- helpers ----------------------------------------------------
typedef float f32x4 __attribute__((ext_vector_type(4)));
typedef __bf16 bf16x8 __attribute__((ext_vector_type(8)));

__device__ __forceinline__ unsigned short f2bf(float f) {
    union { float f; unsigned int u; } v; v.f = f;
    unsigned int u = v.u + 0x7fffu + ((v.u >> 16) & 1u);   // RNE
    return (unsigned short)(u >> 16);
}

#define MFMA(a, b, c) __builtin_amdgcn_mfma_f32_16x16x32_bf16((a), (b), (c), 0, 0, 0)

// ---------------- weight prep: pure gather, hi only --------------------------
// whi layout: [p][w][u]  (u contiguous)
__global__ __launch_bounds__(256) void wprep_kernel(
    const float* __restrict__ w, unsigned short* __restrict__ whi)
{
    int idx = blockIdx.x * 256 + threadIdx.x;
    if (idx >= NPATH * 128 * 128) return;
    int p   = idx / 16384;
    int rem = idx - p * 16384;
    int wc  = rem >> 7;     // w channel
    int u   = rem & 127;
    whi[idx] = f2bf(w[p * 16384 + u * 128 + wc]);
}

// ---------------- pass over NP l1-homogeneous paths (W hi-only) --------------
// B fragments for the pass's NC columns are read ONCE per ub and shared by all
// NP paths. A loaded per (path, ub) -- 4 regs live; compiler hoists next loads
// under the MFMAs.
// D layout (m89-verified): col = lane&15 -> sample n; row = (lane>>4)*4+reg -> w-off.
template<int P0G, int NP, int CB, int NC>
__device__ __forceinline__ void gemm_pass(
    const unsigned short* __restrict__ whi,
    const unsigned short (*sB)[16][136],
    const float* sM35,
    float (&ov)[4][9], int r16, int q4, int wt)
{
    f32x4 acc[NP][NC];
    #pragma unroll
    for (int pp = 0; pp < NP; ++pp)
        #pragma unroll
        for (int i = 0; i < NC; ++i) acc[pp][i] = (f32x4)(0.0f);

    #pragma unroll
    for (int ub = 0; ub < 4; ++ub) {
        const int ko = ub * 32 + q4 * 8;
        bf16x8 B[NC];
        #pragma unroll
        for (int c = 0; c < NC; ++c)
            B[c] = *(const bf16x8*)&sB[CB + c][r16][ko];
        #pragma unroll
        for (int pp = 0; pp < NP; ++pp) {
            const size_t aoff =
                ((size_t)((P0G + pp) * 128 + wt * 16 + r16)) * 128 + ko;
            bf16x8 Ah = *(const bf16x8*)&whi[aoff];
            #pragma unroll
            for (int i = 0; i < NC; ++i)
                acc[pp][i] = MFMA(Ah, B[i], acc[pp][i]);
        }
    }

    // fold into ov (indices identical to round-7/8 verified version)
    #pragma unroll
    for (int pp = 0; pp < NP; ++pp) {
        const int P = P0G + pp;
        #pragma unroll
        for (int i = 0; i < NC; ++i)
            #pragma unroll
            for (int k = 0; k < H_N3[P]; ++k) {
                const float mv = sM35[r16 * 175 + (H_PIB[P] + i) * 5 + k];
                #pragma unroll
                for (int r = 0; r < 4; ++r)
                    ov[r][H_KCB[H_LO[P]] + k] += acc[pp][i][r] * mv;
            }
    }
}

// ---------------- main kernel ------------------------------------------------
// LDS: sB [9][16][136] ushort (39168 B) + sM35 [16*175] f32 (11200 B) = 50368 B
//      epilogue sOut[8][1156] f32 (36992 B) aliases the region, 2 sample-halves.
__global__ __launch_bounds__(NTHREADS, 1) void fctp_kernel(
    const float* __restrict__ x1, const float* __restrict__ x2,
    const unsigned short* __restrict__ whi,
    float* __restrict__ out, int N)
{
    __shared__ __align__(16) unsigned char smem[50368];
    unsigned short (*sB)[16][136] = (unsigned short (*)[16][136])smem;
    float* sM35 = (float*)(smem + 39168);

    const int tid  = threadIdx.x;
    const int lane = tid & 63;
    const int wt   = tid >> 6;
    const int n0   = blockIdx.x * SAMP;

    // ---- stage X1 -> bf16 in sB: DEEP-ISSUE (9 loads in flight, then convert)
    // 16 samples * 288 f32x4 = 4608 = 9 * 512 exactly.
    {
        f32x4 tv[9];
        #pragma unroll
        for (int t = 0; t < 9; ++t) {
            const int e  = tid + t * NTHREADS;
            const int n  = e / 288;
            const int c4 = (e % 288) * 4;
            tv[t] = (n0 + n < N) ? *(const f32x4*)&x1[(size_t)(n0 + n) * SROW + c4]
                                 : (f32x4)(0.0f);
        }
        #pragma unroll
        for (int t = 0; t < 9; ++t) {
            const int e  = tid + t * NTHREADS;
            const int n  = e / 288;
            const int c4 = (e % 288) * 4;
            #pragma unroll
            for (int j = 0; j < 4; ++j) {
                int c = c4 + j;
                int col, u;
                if (c < 128)       { col = 0;           u = c; }
                else if (c < 512)  { int rr = c - 128;  u = rr / 3; col = 1 + rr % 3; }
                else               { int rr = c - 512;  u = rr / 5; col = 4 + rr % 5; }
                sB[col][n][u] = f2bf(tv[t][j]);
            }
        }
    }

    // ---- stage PW * M_p[n,i,k] into sM35 (verified r4, byte-identical) ----
    for (int e = tid; e < SAMP * 115; e += NTHREADS) {
        int n = e / 115, m = e % 115;
        float val = 0.0f;
        int pi5 = 0;
        #pragma unroll
        for (int p = 0; p < NPATH; ++p) {
            if (m >= H_MOFF[p] && m < H_MOFF[p + 1]) {
                const int n2 = H_N2[p], n3 = H_N3[p];
                int rr = m - H_MOFF[p];
                int i = rr / n3, k = rr % n3;
                if (n0 + n < N) {
                    const float* Cp  = c_W3.v + H_W3OFF[p];
                    const float* x2p = x2 + (size_t)(n0 + n) * 9 + H_X2OFF[H_L2[p]];
                    float a = 0.0f;
                    #pragma unroll
                    for (int j = 0; j < n2; ++j)
                        a += Cp[(i * n2 + j) * n3 + k] * x2p[j];
                    val = H_PW[H_LO[p]] * a;
                }
                pi5 = (H_PIB[p] + i) * 5 + k;
            }
        }
        sM35[n * 175 + pi5] = val;
    }
    __syncthreads();

    // ---- MFMA GEMM in 5 l1-homogeneous passes (W hi-only) ----
    const int r16 = lane & 15;   // A row (w-offset) and B col (sample n)
    const int q4  = lane >> 4;

    float ov[4][9];
    #pragma unroll
    for (int r = 0; r < 4; ++r)
        #pragma unroll
        for (int j = 0; j < 9; ++j) ov[r][j] = 0.0f;

    gemm_pass<0, 3, 0, 1>(whi, sB, sM35, ov, r16, q4, wt);  // p0-2, col 0
    gemm_pass<3, 2, 1, 3>(whi, sB, sM35, ov, r16, q4, wt);  // p3,4 cols 1-3
    gemm_pass<5, 2, 1, 3>(whi, sB, sM35, ov, r16, q4, wt);  // p5,6 cols 1-3
    gemm_pass<7, 2, 4, 5>(whi, sB, sM35, ov, r16, q4, wt);  // p7,8 cols 4-8
    gemm_pass<9, 2, 4, 5>(whi, sB, sM35, ov, r16, q4, wt);  // p9,10 cols 4-8

    // ---- two-pass epilogue (verified r7/r8): sOut[8][1156] aliases smem ----
    __syncthreads();
    float* sOut = (float*)smem;
    const int wbase = wt * 16 + q4 * 4;
    #pragma unroll
    for (int half = 0; half < 2; ++half) {
        if ((r16 >> 3) == half) {
            const int nl = r16 & 7;
            float* so = &sOut[nl * 1156];
            #pragma unroll
            for (int r = 0; r < 4; ++r) {
                const int w = wbase + r;
                so[w] = ov[r][0];
                #pragma unroll
                for (int k = 0; k < 3; ++k) so[128 + w * 3 + k] = ov[r][1 + k];
                #pragma unroll
                for (int k = 0; k < 5; ++k) so[512 + w * 5 + k] = ov[r][4 + k];
            }
        }
        __syncthreads();
        for (int e = tid; e < 8 * (SROW / 4); e += NTHREADS) {
            int nn = e / (SROW / 4), c4 = (e % (SROW / 4)) * 4;
            int n = half * 8 + nn;
            if (n0 + n < N)
                *(f32x4*)&out[(size_t)(n0 + n) * SROW + c4] =
                    *(const f32x4*)&sOut[nn * 1156 + c4];
        }
        __syncthreads();
    }
}

// ---------------- launch -----------------------------------------------------
extern "C" void kernel_launch(void* const* d_in, const int* in_sizes, int n_in,
                              void* d_out, int out_size, void* d_ws, size_t ws_size,
                              hipStream_t stream) {
    const float* x1 = (const float*)d_in[0];
    const float* x2 = (const float*)d_in[1];
    const float* wt = (const float*)d_in[2];
    float* out = (float*)d_out;

    unsigned short* whi = (unsigned short*)d_ws;

    int N = in_sizes[0] / SROW;

    hipLaunchKernelGGL(wprep_kernel, dim3((NPATH * 128 * 128 + 255) / 256),
                       dim3(256), 0, stream, wt, whi);

    int blocks = (N + SAMP - 1) / SAMP;
    hipLaunchKernelGGL(fctp_kernel, dim3(blocks), dim3(NTHREADS), 0, stream,
                       x1, x2, whi, out, N);
}